// Round 11
// baseline (251.608 us; speedup 1.0000x reference)
//
#include <hip/hip_runtime.h>

// DynamicFilter: out[b,c,h,w] = sum_p (y[c*9+p] + bias[c*9+p]) * x[b,c,h+dh,w+dw]
//   y[o] = sum_c' x[b,c',h,w] * W[o,c']   (GEMM M=65536, N=2304, K=256, bf16 MFMA)
// B=4, C=256, H=W=128, 9 taps.
// R12 (125us dfgemm): 16px/wave, grid 512x512thr, occupancy 39%, VGPR 60,
//   conflicts 0. Pipe mins: MFMA 32us, LDS 31us, VALU 34us -> 125us means
//   serialization: 112 block-wide barriers (7/chunk) with only 12-MFMA
//   phases, plus 76-VMEM epilogue per chunk.
// R13: (a) 3 phases/chunk, ring-6 FIXED slots (sub j -> buf j, 73728 B,
//   still 2 blocks/CU): P0{stage 4,5(cur); M0,M1} P1{stage 0',1'; M2,M3}
//   P2{stage 2',3'; M4,M5} epi. Prefetch distance 2 phases. Waits derived:
//   P0 VM(4) (<=4 epi stores), P1 VM(8) (depth bound only), P2 VM(4)
//   (retires stores+S_P0 -> subs4,5 landed; S_P1 flies). Per-buf WAR: read
//   at Pk, restaged at Pk+1 behind that SYNC's lgkm-drain+barrier.
//   (b) T5 setprio(1) around each 24-MFMA cluster. (c) bias as 9 x float4
//   (lane's 4 channels x 9 taps = 36 contiguous floats, 144B-aligned).
//   (d) bijective XCD-chunked swizzle (512 = 8*64): h-adjacent blocks share
//   an XCD L2 -> patch rows (h+-1) become L2 hits.

typedef __attribute__((ext_vector_type(8))) short bf16x8;   // 8 bf16 = 4 VGPRs
typedef __attribute__((ext_vector_type(4))) float f32x4;    // MFMA 16x16 acc

__device__ __forceinline__ unsigned int f2bf(float f) {
    unsigned int u = __float_as_uint(f);
    return (u + 0x7fffu + ((u >> 16) & 1u)) >> 16;   // RNE
}
__device__ __forceinline__ unsigned int pack2(float a, float b) {
    return f2bf(a) | (f2bf(b) << 16);
}

// ---------------------------------------------------------------------------
// Kernel 1: W (2304x256 fp32) -> Wb bf16, instruction-ordered A-fragments
// with channel-aligned out permutation (unchanged from R11/R12):
//   o: chunk=o/144, oc=o%144, c_local=oc/9, p=oc%9
//   q=c_local/4, c4=c_local%4, idx=c4*9+p, ni=idx/4, j=idx%4, r=q*4+j
//   k: kh=k/128, s=(k%128)/32, kq=(k%32)/8, e=k%8; jsub=kh*3+ni/3; ni_=ni%3
//   dst = chunk*73728 + jsub*12288 + (s*3+ni_)*1024 + (kq*16+r)*16 + e*2
// ---------------------------------------------------------------------------
__global__ __launch_bounds__(256) void wconv_kernel(const float* __restrict__ W,
                                                    unsigned char* __restrict__ Wb) {
    int idx0 = blockIdx.x * 256 + threadIdx.x;   // 73728 = 2304 * 32 groups
    int o = idx0 >> 5, g = idx0 & 31;
    const float4* src = (const float4*)(W + ((size_t)o << 8) + ((size_t)g << 3));
    float4 v0 = src[0], v1 = src[1];
    uint4 pk;
    pk.x = pack2(v0.x, v0.y); pk.y = pack2(v0.z, v0.w);
    pk.z = pack2(v1.x, v1.y); pk.w = pack2(v1.z, v1.w);
    int kh = g >> 4, g2 = g & 15, s = g2 >> 2, kq = g2 & 3;
    int chunk = o / 144, oc = o - chunk * 144;
    int c_local = oc / 9, p = oc - c_local * 9;
    int q = c_local >> 2, c4 = c_local & 3;
    int idx = c4 * 9 + p;
    int ni = idx >> 2, j = idx & 3, r = (q << 2) + j;
    int jsub = kh * 3 + ni / 3, ni_ = ni % 3;
    size_t dst = (size_t)chunk * 73728 + (size_t)jsub * 12288
               + (size_t)(s * 3 + ni_) * 1024 + (size_t)((kq << 4) + r) * 16;
    *(uint4*)(Wb + dst) = pk;
}

// ---------------------------------------------------------------------------
// Kernel 2. LDS: 6 fixed bufs, buf j at j*12288 (sub j of any chunk). 73728 B.
// ---------------------------------------------------------------------------

#define SYNC_VM(N) asm volatile("s_waitcnt vmcnt(" #N ") lgkmcnt(0)\n\ts_barrier" ::: "memory")
#define FENCE      asm volatile("" ::: "memory")   // compile-time order pin only

// Stage sub-tile J of chunk CH into FIXED buf J. Slices of 2048 B; wave wv
// stages slice wv%6 with 2 x global_load_lds(16B); waves 6,7 duplicate
// slices 0,1 (identical bytes). Per-wave vmcnt += 2, uniform across waves.
#define STAGE(CH, J)                                                            \
    do {                                                                        \
        const int sl_ = (wv < 6) ? wv : (wv - 6);                               \
        const unsigned char* bs_ = Wb + (size_t)(CH) * 73728                    \
            + (size_t)(J) * 12288 + sl_ * 2048 + (lane << 4);                   \
        unsigned char* bd_ = smem + (size_t)(J) * 12288 + sl_ * 2048;           \
        __builtin_amdgcn_global_load_lds(                                       \
            (const __attribute__((address_space(1))) void*)(bs_),               \
            (__attribute__((address_space(3))) void*)(bd_), 16, 0, 0);          \
        __builtin_amdgcn_global_load_lds(                                       \
            (const __attribute__((address_space(1))) void*)(bs_ + 1024),        \
            (__attribute__((address_space(3))) void*)(bd_ + 1024), 16, 0, 0);   \
    } while (0)

// 12 MFMAs on sub-tile J (3 ni x 4 s, single 16-px M-tile). A = Wb fragment
// (uniform base + lane*16, conflict-free), B = afr (pixel operand).
// acc[ni] = C[out_row][px_col]: col=lane&15=px, row=quad*4+reg=out-slot.
#define MFMA_SUB(J)                                                             \
    do {                                                                        \
        const int kh_ = (J) / 3, snib_ = ((J) % 3) * 3;                         \
        const unsigned char* bb_ = smem + (size_t)(J) * 12288 + (lane << 4);    \
        _Pragma("unroll")                                                       \
        for (int s_ = 0; s_ < 4; ++s_) {                                        \
            const bf16x8 a_ = afr[(kh_ << 2) + s_];                             \
            _Pragma("unroll")                                                   \
            for (int ni_ = 0; ni_ < 3; ++ni_) {                                 \
                const bf16x8 bq_ = *(const bf16x8*)(bb_ + ((s_ * 3 + ni_) << 10)); \
                acc[snib_ + ni_] = __builtin_amdgcn_mfma_f32_16x16x32_bf16(     \
                    bq_, a_, acc[snib_ + ni_], 0, 0, 0);                        \
            }                                                                   \
        }                                                                       \
    } while (0)

__global__ __launch_bounds__(512, 4) void dfgemm_kernel(
        const unsigned char* __restrict__ Wb, const float* __restrict__ x,
        const float* __restrict__ bias, float* __restrict__ out) {
    __shared__ __align__(16) unsigned char smem[73728];

    const int t = threadIdx.x;
    const int lane = t & 63, wv = t >> 6;        // wv 0..7
    const int quad = lane >> 4, lrow = lane & 15;

    // XCD-chunked bijective swizzle (512 = 8 XCDs x 64): blocks with the same
    // bid%8 land on one XCD and cover 64 consecutive rows -> h+-1 patch rows
    // are L2-local. b = image, h = row.
    const int swz = ((blockIdx.x & 7) << 6) + (blockIdx.x >> 3);
    const int b = swz >> 7;                      // image 0..3
    const int h = swz & 127;                     // row
    const int w = (wv << 4) + lrow;              // this lane's pixel (16/wave)

    // Warm the pipeline: chunk 0 subs 0..3 in flight while afr loads run.
    STAGE(0, 0); STAGE(0, 1); STAGE(0, 2); STAGE(0, 3);

    // ---- A(pixel) fragments direct from x: afr[gg][e] = bf16(x[b, gg*32+quad*8+e, h, w]) ----
    bf16x8 afr[8];
    {
        const float* xrow = x + ((size_t)b << 22) + (h << 7);
        #pragma unroll
        for (int gg = 0; gg < 8; ++gg) {
            const float* p = xrow + ((size_t)((gg << 5) + (quad << 3)) << 14) + w;
            float v[8];
            #pragma unroll
            for (int e = 0; e < 8; ++e) v[e] = p[(size_t)e << 14];
            uint4 pk;
            pk.x = pack2(v[0], v[1]); pk.y = pack2(v[2], v[3]);
            pk.z = pack2(v[4], v[5]); pk.w = pack2(v[6], v[7]);
            afr[gg] = *(const bf16x8*)&pk;
        }
    }
    SYNC_VM(0);                        // prologue only: subs 0-3 landed, full drain

    #pragma unroll 1
    for (int chunk = 0; chunk < 16; ++chunk) {
        const int c1 = (chunk + 1) & 15;         // tail wraps: harmless re-stage
        f32x4 acc[9];
        const f32x4 zero = {0.f, 0.f, 0.f, 0.f};
        #pragma unroll
        for (int ni = 0; ni < 9; ++ni) acc[ni] = zero;

        // P0: bufs0,1 staged at [c-1,P1], retired during prior epilogue
        // (consumed bias/patch loads force in-order retirement). VM(4) just
        // bounds the <=4 outstanding out-stores.
        SYNC_VM(4);
        STAGE(chunk, 4); STAGE(chunk, 5);      // for P2 of THIS chunk (dist 2)
        __builtin_amdgcn_s_setprio(1);
        MFMA_SUB(0); MFMA_SUB(1);
        __builtin_amdgcn_s_setprio(0);

        // P1: bufs2,3 staged [c-1,P2], retired during epilogue. VM(8) allows
        // stores + S_P0 to stay in flight (nothing new needed here).
        SYNC_VM(8);
        STAGE(c1, 0); STAGE(c1, 1);            // bufs0,1 read-drained at P0
        __builtin_amdgcn_s_setprio(1);
        MFMA_SUB(2); MFMA_SUB(3);
        __builtin_amdgcn_s_setprio(0);

        // P2: need S_P0 (subs4,5). Outstanding: stores(old) + S_P0 + S_P1;
        // VM(4) retires stores+S_P0 (in-order), leaves S_P1 flying.
        SYNC_VM(4);
        STAGE(c1, 2); STAGE(c1, 3);            // bufs2,3 read-drained at P1
        __builtin_amdgcn_s_setprio(1);
        MFMA_SUB(4); MFMA_SUB(5);
        __builtin_amdgcn_s_setprio(0);
        FENCE;                                 // pin stages BEFORE epi loads

        // ---- epilogue: pure-register. Lane owns pixel w and 4 whole
        //      channels (quad*4+c4). Bias: 36 contiguous floats (144B-aligned)
        //      = 9 x float4. acc slot for (c4,p): idx=c4*9+p, ni=idx/4,
        //      j=idx%4 — all compile-time. No LDS, no barriers. ----
        float bb[36];
        {
            const float4* bsrc = (const float4*)(bias + ((chunk << 4) + (quad << 2)) * 9);
            #pragma unroll
            for (int i = 0; i < 9; ++i) *(float4*)(bb + 4 * i) = bsrc[i];
        }
        #pragma unroll
        for (int c4 = 0; c4 < 4; ++c4) {
            const int cg = (chunk << 4) + (quad << 2) + c4;  // channel
            const float* xc = x + ((size_t)((b << 8) + cg) << 14);
            float sum = 0.f;
            #pragma unroll
            for (int p = 0; p < 9; ++p) {
                const int idx = c4 * 9 + p;
                const int ni = idx >> 2, j = idx & 3;
                const float yv = acc[ni][j];
                const int hh = h + p / 3 - 1, ww = w + p % 3 - 1;
                float xv = 0.f;
                if ((unsigned)hh < 128u && (unsigned)ww < 128u)
                    xv = xc[(hh << 7) + ww];                 // fp32 patch
                sum += (yv + bb[idx]) * xv;
            }
            out[((size_t)((b << 8) + cg) << 14) + (h << 7) + w] = sum;
        }
    }
}

extern "C" void kernel_launch(void* const* d_in, const int* in_sizes, int n_in,
                              void* d_out, int out_size, void* d_ws, size_t ws_size,
                              hipStream_t stream) {
    const float* x    = (const float*)d_in[0];   // 4*256*128*128
    const float* W    = (const float*)d_in[1];   // 2304*256
    const float* bias = (const float*)d_in[2];   // 2304
    float* out = (float*)d_out;

    unsigned char* Wb = (unsigned char*)d_ws;    // 1,179,648 B

    wconv_kernel<<<288, 256, 0, stream>>>(W, Wb);
    dfgemm_kernel<<<512, 512, 0, stream>>>(Wb, x, bias, out);
}

// Round 12
// 210.181 us; speedup vs baseline: 1.1971x; 1.1971x over previous
//
#include <hip/hip_runtime.h>

// DynamicFilter: out[b,c,h,w] = sum_p (y[c*9+p] + bias[c*9+p]) * x[b,c,h+dh,w+dw]
//   y[o] = sum_c' x[b,c',h,w] * W[o,c']   (GEMM M=65536, N=2304, K=256, bf16 MFMA)
// B=4, C=256, H=W=128, 9 taps.
// R12 125us. R13 (3-phase+setprio+swizzle, 2-phase prefetch) 175us REGRESSION.
// Model that fits R4..R13: LDS READ BW. Each wave reads the whole 73728-B Wb
//   tile per chunk; traffic = (65536/ppw) waves x 1.18 MB. R12 ppw=16: 4.8 GB
//   = ~93us of LDS pipe in a 125us kernel (74% busy) = the wall.
// R14: ppw 16->32 (each ds_read_b128 feeds 2 MFMAs; traffic halves to 2.4 GB
//   ~ 46us) while keeping R12's lean structure: 256-thr/4-wave blocks, grid
//   512 (1 row/block), 2 blocks/CU (block-level GEMM||epilogue overlap),
//   register-only epilogue, ring-6 FIXED slots (73728 B; 2x = 147K <= 160K).
//   Schedule: phK (K=1..5) stages next-chunk sub K-1 (overwrites the buf read
//   at phK-1, behind phK's lgkm-drain barrier); sub5 staged pre-epilogue
//   behind SYNC_LG + FENCE. ALL stage->use distances >= 4 phases + epilogue
//   (R13's fatal 2-phase distances eliminated). STAGE = 3 x 16-B gload_lds
//   (+3 vm/wave). Waits VM(8/8/11/14/17/20): pure upper bounds, no steady-
//   state stalls; buf readiness enforced by the epilogue's consumed patch
//   loads (in-order vm retirement; FENCE pins the pre-epi stage before them).
//   No setprio, no swizzle, scalar bias (R13 suspects removed).

typedef __attribute__((ext_vector_type(8))) short bf16x8;   // 8 bf16 = 4 VGPRs
typedef __attribute__((ext_vector_type(4))) float f32x4;    // MFMA 16x16 acc

__device__ __forceinline__ unsigned int f2bf(float f) {
    unsigned int u = __float_as_uint(f);
    return (u + 0x7fffu + ((u >> 16) & 1u)) >> 16;   // RNE
}
__device__ __forceinline__ unsigned int pack2(float a, float b) {
    return f2bf(a) | (f2bf(b) << 16);
}

// ---------------------------------------------------------------------------
// Kernel 1: W (2304x256 fp32) -> Wb bf16, instruction-ordered A-fragments
// with channel-aligned out permutation (unchanged from R11/R12):
//   o: chunk=o/144, oc=o%144, c_local=oc/9, p=oc%9
//   q=c_local/4, c4=c_local%4, idx=c4*9+p, ni=idx/4, j=idx%4, r=q*4+j
//   k: kh=k/128, s=(k%128)/32, kq=(k%32)/8, e=k%8; jsub=kh*3+ni/3; ni_=ni%3
//   dst = chunk*73728 + jsub*12288 + (s*3+ni_)*1024 + (kq*16+r)*16 + e*2
// ---------------------------------------------------------------------------
__global__ __launch_bounds__(256) void wconv_kernel(const float* __restrict__ W,
                                                    unsigned char* __restrict__ Wb) {
    int idx0 = blockIdx.x * 256 + threadIdx.x;   // 73728 = 2304 * 32 groups
    int o = idx0 >> 5, g = idx0 & 31;
    const float4* src = (const float4*)(W + ((size_t)o << 8) + ((size_t)g << 3));
    float4 v0 = src[0], v1 = src[1];
    uint4 pk;
    pk.x = pack2(v0.x, v0.y); pk.y = pack2(v0.z, v0.w);
    pk.z = pack2(v1.x, v1.y); pk.w = pack2(v1.z, v1.w);
    int kh = g >> 4, g2 = g & 15, s = g2 >> 2, kq = g2 & 3;
    int chunk = o / 144, oc = o - chunk * 144;
    int c_local = oc / 9, p = oc - c_local * 9;
    int q = c_local >> 2, c4 = c_local & 3;
    int idx = c4 * 9 + p;
    int ni = idx >> 2, j = idx & 3, r = (q << 2) + j;
    int jsub = kh * 3 + ni / 3, ni_ = ni % 3;
    size_t dst = (size_t)chunk * 73728 + (size_t)jsub * 12288
               + (size_t)(s * 3 + ni_) * 1024 + (size_t)((kq << 4) + r) * 16;
    *(uint4*)(Wb + dst) = pk;
}

// ---------------------------------------------------------------------------
// Kernel 2. LDS: 6 fixed bufs, buf j at j*12288 (sub j of current chunk).
// Total 73728 B -> 2 blocks/CU. 4 waves x 32 px (2 mi halves) = 128 px row.
// ---------------------------------------------------------------------------

#define SYNC_VM(N) asm volatile("s_waitcnt vmcnt(" #N ") lgkmcnt(0)\n\ts_barrier" ::: "memory")
#define SYNC_LG    asm volatile("s_waitcnt lgkmcnt(0)\n\ts_barrier" ::: "memory")
#define FENCE      asm volatile("" ::: "memory")   // compile-time order pin only

// Stage sub-tile J of chunk CH into FIXED buf J. Wave wv stages 3072 B as
// 3 x global_load_lds(16B) (4 waves x 3072 = 12288). Per-wave vmcnt += 3.
#define STAGE(CH, J)                                                            \
    do {                                                                        \
        const unsigned char* bs_ = Wb + (size_t)(CH) * 73728                    \
            + (size_t)(J) * 12288 + wv * 3072 + (lane << 4);                    \
        unsigned char* bd_ = smem + (size_t)(J) * 12288 + wv * 3072;            \
        _Pragma("unroll")                                                       \
        for (int c_ = 0; c_ < 3; ++c_)                                          \
            __builtin_amdgcn_global_load_lds(                                   \
                (const __attribute__((address_space(1))) void*)(bs_ + c_ * 1024), \
                (__attribute__((address_space(3))) void*)(bd_ + c_ * 1024), 16, 0, 0); \
    } while (0)

// 24 MFMAs on sub-tile J (3 ni x 4 s x 2 mi) sharing 12 ds_read_b128 (each
// bq feeds both mi halves -- the ppw=32 reuse). A = Wb fragment (uniform
// base + lane*16, conflict-free), B = afr (pixel operand).
// acc[mi][ni] = C[out_row][px_col]: col=lane&15=px, row=quad*4+reg=out-slot.
#define MFMA_SUB(J)                                                             \
    do {                                                                        \
        const int kh_ = (J) / 3, snib_ = ((J) % 3) * 3;                         \
        const unsigned char* bb_ = smem + (size_t)(J) * 12288 + (lane << 4);    \
        _Pragma("unroll")                                                       \
        for (int s_ = 0; s_ < 4; ++s_) {                                        \
            const bf16x8 a0_ = afr[(kh_ << 2) + s_];                            \
            const bf16x8 a1_ = afr[8 + (kh_ << 2) + s_];                        \
            _Pragma("unroll")                                                   \
            for (int ni_ = 0; ni_ < 3; ++ni_) {                                 \
                const bf16x8 bq_ = *(const bf16x8*)(bb_ + ((s_ * 3 + ni_) << 10)); \
                acc[0][snib_ + ni_] = __builtin_amdgcn_mfma_f32_16x16x32_bf16(  \
                    bq_, a0_, acc[0][snib_ + ni_], 0, 0, 0);                    \
                acc[1][snib_ + ni_] = __builtin_amdgcn_mfma_f32_16x16x32_bf16(  \
                    bq_, a1_, acc[1][snib_ + ni_], 0, 0, 0);                    \
            }                                                                   \
        }                                                                       \
    } while (0)

__global__ __launch_bounds__(256, 2) void dfgemm_kernel(
        const unsigned char* __restrict__ Wb, const float* __restrict__ x,
        const float* __restrict__ bias, float* __restrict__ out) {
    __shared__ __align__(16) unsigned char smem[73728];

    const int t = threadIdx.x;
    const int lane = t & 63, wv = t >> 6;        // wv 0..3
    const int quad = lane >> 4, lrow = lane & 15;

    const int b = blockIdx.x >> 7;               // image 0..3
    const int h = blockIdx.x & 127;              // row
    // wave covers px [wv*32, wv*32+32): mi half 0 = +0..15, half 1 = +16..31

    // Warm the pipeline: all 6 subs of chunk 0 in flight while afr loads run.
    STAGE(0, 0); STAGE(0, 1); STAGE(0, 2);
    STAGE(0, 3); STAGE(0, 4); STAGE(0, 5);

    // ---- A(pixel) fragments: afr[mi*8+kh*4+s][e] = bf16(x[b, ch, h, w]) ----
    bf16x8 afr[16];
    {
        const float* xrow = x + ((size_t)b << 22) + (h << 7);
        #pragma unroll
        for (int mi = 0; mi < 2; ++mi) {
            const int w = (wv << 5) + (mi << 4) + lrow;
            #pragma unroll
            for (int gg = 0; gg < 8; ++gg) {
                const float* p = xrow + ((size_t)((gg << 5) + (quad << 3)) << 14) + w;
                float v[8];
                #pragma unroll
                for (int e = 0; e < 8; ++e) v[e] = p[(size_t)e << 14];
                uint4 pk;
                pk.x = pack2(v[0], v[1]); pk.y = pack2(v[2], v[3]);
                pk.z = pack2(v[4], v[5]); pk.w = pack2(v[6], v[7]);
                afr[(mi << 3) + gg] = *(const bf16x8*)&pk;
            }
        }
    }
    SYNC_VM(0);                        // prologue only: subs 0-5 landed, full drain

    #pragma unroll 1
    for (int chunk = 0; chunk < 16; ++chunk) {
        const int c1 = (chunk + 1) & 15;         // tail wraps: harmless re-stage
        f32x4 acc[2][9];
        const f32x4 zero = {0.f, 0.f, 0.f, 0.f};
        #pragma unroll
        for (int mi = 0; mi < 2; ++mi)
            #pragma unroll
            for (int ni = 0; ni < 9; ++ni) acc[mi][ni] = zero;

        // All bufs for THIS chunk were staged >=4 phases + one epilogue ago
        // and are force-retired by the prior epilogue's consumed patch loads.
        // VM(N) values are slack upper bounds (8 stores + stages in flight).
        SYNC_VM(8);                            // ph0 (no stage)
        MFMA_SUB(0);

        SYNC_VM(8);                            // ph1
        STAGE(c1, 0);                          // buf0: readers (ph0) drained
        MFMA_SUB(1);

        SYNC_VM(11);                           // ph2
        STAGE(c1, 1);                          // buf1: readers (ph1) drained
        MFMA_SUB(2);

        SYNC_VM(14);                           // ph3
        STAGE(c1, 2);                          // buf2
        MFMA_SUB(3);

        SYNC_VM(17);                           // ph4
        STAGE(c1, 3);                          // buf3
        MFMA_SUB(4);

        SYNC_VM(20);                           // ph5
        STAGE(c1, 4);                          // buf4
        MFMA_SUB(5);

        SYNC_LG;                               // ph5 readers of buf5 drained
        STAGE(c1, 5);                          // buf5; lands during epilogue
        FENCE;                                 // pin stage BEFORE epi loads

        // ---- epilogue: pure-register. Lane owns pixels w(mi) and 4 whole
        //      channels (quad*4+c4); acc slot for (c4,p): idx=c4*9+p,
        //      ni=idx/4, j=idx%4 -- all compile-time. No LDS. ----
        #pragma unroll
        for (int mi = 0; mi < 2; ++mi) {
            const int w = (wv << 5) + (mi << 4) + lrow;      // this lane's pixel
            #pragma unroll
            for (int c4 = 0; c4 < 4; ++c4) {
                const int cg = (chunk << 4) + (quad << 2) + c4;  // channel
                const float* bp = bias + cg * 9;
                const float* xc = x + ((size_t)((b << 8) + cg) << 14);
                float sum = 0.f;
                #pragma unroll
                for (int p = 0; p < 9; ++p) {
                    const int idx = c4 * 9 + p;
                    const int ni = idx >> 2, j = idx & 3;
                    const float yv = acc[mi][ni][j];
                    const int hh = h + p / 3 - 1, ww = w + p % 3 - 1;
                    float xv = 0.f;
                    if ((unsigned)hh < 128u && (unsigned)ww < 128u)
                        xv = xc[(hh << 7) + ww];             // fp32 patch
                    sum += (yv + bp[p]) * xv;
                }
                out[((size_t)((b << 8) + cg) << 14) + (h << 7) + w] = sum;
            }
        }
    }
}

extern "C" void kernel_launch(void* const* d_in, const int* in_sizes, int n_in,
                              void* d_out, int out_size, void* d_ws, size_t ws_size,
                              hipStream_t stream) {
    const float* x    = (const float*)d_in[0];   // 4*256*128*128
    const float* W    = (const float*)d_in[1];   // 2304*256
    const float* bias = (const float*)d_in[2];   // 2304
    float* out = (float*)d_out;

    unsigned char* Wb = (unsigned char*)d_ws;    // 1,179,648 B

    wconv_kernel<<<288, 256, 0, stream>>>(W, Wb);
    dfgemm_kernel<<<512, 256, 0, stream>>>(Wb, x, bias, out);
}

// Round 13
// 204.136 us; speedup vs baseline: 1.2325x; 1.0296x over previous
//
#include <hip/hip_runtime.h>

// DynamicFilter: out[b,c,h,w] = sum_p (y[c*9+p] + bias[c*9+p]) * x[b,c,h+dh,w+dw]
//   y[o] = sum_c' x[b,c',h,w] * W[o,c']   (GEMM M=65536, N=2304, K=256, bf16 MFMA)
// B=4, C=256, H=W=128, 9 taps.
// R12 125us (ppw16, 16 waves/CU, LDS 74% busy). R14 134us (ppw32, 8 waves/CU,
//   all pipes <=34% -> latency-bound). LDS-BW alone is NOT the wall: halving
//   traffic lost 9us because hiding halved. R14's stall source: 7 block-wide
//   barriers per chunk (112 total), each only 24 MFMAs apart, at 2 waves/SIMD.
// R15 = R14 with 2 barriers/chunk: {top SYNC_VM(8)} GEMM 6 subs straight-line
//   (72 ds_read + 144 MFMA, compiler lgkm, 18 acc chains) {SYNC_LG} stage all
//   6 next-chunk subs, FENCE, epilogue. Retirement spine unchanged: stages
//   issue before epilogue's consumed patch loads -> force-retired before the
//   wave reaches the top barrier; SYNC_VM(8) bounds only the <=8 stores.
//   WAR: SYNC_LG drains all B-reads before restaging. Stage->use distance =
//   full epilogue + barrier. Everything else byte-identical to R14.

typedef __attribute__((ext_vector_type(8))) short bf16x8;   // 8 bf16 = 4 VGPRs
typedef __attribute__((ext_vector_type(4))) float f32x4;    // MFMA 16x16 acc

__device__ __forceinline__ unsigned int f2bf(float f) {
    unsigned int u = __float_as_uint(f);
    return (u + 0x7fffu + ((u >> 16) & 1u)) >> 16;   // RNE
}
__device__ __forceinline__ unsigned int pack2(float a, float b) {
    return f2bf(a) | (f2bf(b) << 16);
}

// ---------------------------------------------------------------------------
// Kernel 1: W (2304x256 fp32) -> Wb bf16, instruction-ordered A-fragments
// with channel-aligned out permutation (unchanged from R11..R14):
//   o: chunk=o/144, oc=o%144, c_local=oc/9, p=oc%9
//   q=c_local/4, c4=c_local%4, idx=c4*9+p, ni=idx/4, j=idx%4, r=q*4+j
//   k: kh=k/128, s=(k%128)/32, kq=(k%32)/8, e=k%8; jsub=kh*3+ni/3; ni_=ni%3
//   dst = chunk*73728 + jsub*12288 + (s*3+ni_)*1024 + (kq*16+r)*16 + e*2
// ---------------------------------------------------------------------------
__global__ __launch_bounds__(256) void wconv_kernel(const float* __restrict__ W,
                                                    unsigned char* __restrict__ Wb) {
    int idx0 = blockIdx.x * 256 + threadIdx.x;   // 73728 = 2304 * 32 groups
    int o = idx0 >> 5, g = idx0 & 31;
    const float4* src = (const float4*)(W + ((size_t)o << 8) + ((size_t)g << 3));
    float4 v0 = src[0], v1 = src[1];
    uint4 pk;
    pk.x = pack2(v0.x, v0.y); pk.y = pack2(v0.z, v0.w);
    pk.z = pack2(v1.x, v1.y); pk.w = pack2(v1.z, v1.w);
    int kh = g >> 4, g2 = g & 15, s = g2 >> 2, kq = g2 & 3;
    int chunk = o / 144, oc = o - chunk * 144;
    int c_local = oc / 9, p = oc - c_local * 9;
    int q = c_local >> 2, c4 = c_local & 3;
    int idx = c4 * 9 + p;
    int ni = idx >> 2, j = idx & 3, r = (q << 2) + j;
    int jsub = kh * 3 + ni / 3, ni_ = ni % 3;
    size_t dst = (size_t)chunk * 73728 + (size_t)jsub * 12288
               + (size_t)(s * 3 + ni_) * 1024 + (size_t)((kq << 4) + r) * 16;
    *(uint4*)(Wb + dst) = pk;
}

// ---------------------------------------------------------------------------
// Kernel 2. LDS: 6 fixed bufs, buf j at j*12288 (sub j of current chunk).
// Total 73728 B -> 2 blocks/CU. 4 waves x 32 px (2 mi halves) = 128 px row.
// ---------------------------------------------------------------------------

#define SYNC_VM(N) asm volatile("s_waitcnt vmcnt(" #N ") lgkmcnt(0)\n\ts_barrier" ::: "memory")
#define SYNC_LG    asm volatile("s_waitcnt lgkmcnt(0)\n\ts_barrier" ::: "memory")
#define FENCE      asm volatile("" ::: "memory")   // compile-time order pin only

// Stage sub-tile J of chunk CH into FIXED buf J. Wave wv stages 3072 B as
// 3 x global_load_lds(16B) (4 waves x 3072 = 12288). Per-wave vmcnt += 3.
#define STAGE(CH, J)                                                            \
    do {                                                                        \
        const unsigned char* bs_ = Wb + (size_t)(CH) * 73728                    \
            + (size_t)(J) * 12288 + wv * 3072 + (lane << 4);                    \
        unsigned char* bd_ = smem + (size_t)(J) * 12288 + wv * 3072;            \
        _Pragma("unroll")                                                       \
        for (int c_ = 0; c_ < 3; ++c_)                                          \
            __builtin_amdgcn_global_load_lds(                                   \
                (const __attribute__((address_space(1))) void*)(bs_ + c_ * 1024), \
                (__attribute__((address_space(3))) void*)(bd_ + c_ * 1024), 16, 0, 0); \
    } while (0)

// 24 MFMAs on sub-tile J (3 ni x 4 s x 2 mi) sharing 12 ds_read_b128 (each
// bq feeds both mi halves -- the ppw=32 reuse). A = Wb fragment (uniform
// base + lane*16, conflict-free), B = afr (pixel operand).
// acc[mi][ni] = C[out_row][px_col]: col=lane&15=px, row=quad*4+reg=out-slot.
#define MFMA_SUB(J)                                                             \
    do {                                                                        \
        const int kh_ = (J) / 3, snib_ = ((J) % 3) * 3;                         \
        const unsigned char* bb_ = smem + (size_t)(J) * 12288 + (lane << 4);    \
        _Pragma("unroll")                                                       \
        for (int s_ = 0; s_ < 4; ++s_) {                                        \
            const bf16x8 a0_ = afr[(kh_ << 2) + s_];                            \
            const bf16x8 a1_ = afr[8 + (kh_ << 2) + s_];                        \
            _Pragma("unroll")                                                   \
            for (int ni_ = 0; ni_ < 3; ++ni_) {                                 \
                const bf16x8 bq_ = *(const bf16x8*)(bb_ + ((s_ * 3 + ni_) << 10)); \
                acc[0][snib_ + ni_] = __builtin_amdgcn_mfma_f32_16x16x32_bf16(  \
                    bq_, a0_, acc[0][snib_ + ni_], 0, 0, 0);                    \
                acc[1][snib_ + ni_] = __builtin_amdgcn_mfma_f32_16x16x32_bf16(  \
                    bq_, a1_, acc[1][snib_ + ni_], 0, 0, 0);                    \
            }                                                                   \
        }                                                                       \
    } while (0)

__global__ __launch_bounds__(256, 2) void dfgemm_kernel(
        const unsigned char* __restrict__ Wb, const float* __restrict__ x,
        const float* __restrict__ bias, float* __restrict__ out) {
    __shared__ __align__(16) unsigned char smem[73728];

    const int t = threadIdx.x;
    const int lane = t & 63, wv = t >> 6;        // wv 0..3
    const int quad = lane >> 4, lrow = lane & 15;

    const int b = blockIdx.x >> 7;               // image 0..3
    const int h = blockIdx.x & 127;              // row
    // wave covers px [wv*32, wv*32+32): mi half 0 = +0..15, half 1 = +16..31

    // Warm the pipeline: all 6 subs of chunk 0 in flight while afr loads run.
    STAGE(0, 0); STAGE(0, 1); STAGE(0, 2);
    STAGE(0, 3); STAGE(0, 4); STAGE(0, 5);

    // ---- A(pixel) fragments: afr[mi*8+kh*4+s][e] = bf16(x[b, ch, h, w]) ----
    bf16x8 afr[16];
    {
        const float* xrow = x + ((size_t)b << 22) + (h << 7);
        #pragma unroll
        for (int mi = 0; mi < 2; ++mi) {
            const int w = (wv << 5) + (mi << 4) + lrow;
            #pragma unroll
            for (int gg = 0; gg < 8; ++gg) {
                const float* p = xrow + ((size_t)((gg << 5) + (quad << 3)) << 14) + w;
                float v[8];
                #pragma unroll
                for (int e = 0; e < 8; ++e) v[e] = p[(size_t)e << 14];
                uint4 pk;
                pk.x = pack2(v[0], v[1]); pk.y = pack2(v[2], v[3]);
                pk.z = pack2(v[4], v[5]); pk.w = pack2(v[6], v[7]);
                afr[(mi << 3) + gg] = *(const bf16x8*)&pk;
            }
        }
    }
    SYNC_VM(0);                        // prologue only: subs 0-5 landed, full drain

    #pragma unroll 1
    for (int chunk = 0; chunk < 16; ++chunk) {
        const int c1 = (chunk + 1) & 15;         // tail wraps: harmless re-stage
        f32x4 acc[2][9];
        const f32x4 zero = {0.f, 0.f, 0.f, 0.f};
        #pragma unroll
        for (int mi = 0; mi < 2; ++mi)
            #pragma unroll
            for (int ni = 0; ni < 9; ++ni) acc[mi][ni] = zero;

        // Top barrier: this chunk's 6 bufs were staged last iteration and
        // force-retired by that epilogue's consumed patch loads (in-order
        // vmcnt); barrier makes all waves' slices visible. VM(8) bounds only
        // the <=8 outstanding out-stores -> no steady-state stall.
        SYNC_VM(8);

        // ---- GEMM: 6 sub-tiles straight-line, no intra-chunk barriers.
        //      72 ds_read_b128 + 144 MFMA, compiler-scheduled lgkmcnt. ----
        MFMA_SUB(0); MFMA_SUB(1); MFMA_SUB(2);
        MFMA_SUB(3); MFMA_SUB(4); MFMA_SUB(5);

        SYNC_LG;                               // all waves' B-reads drained (WAR)

        // ---- stage ALL of next chunk (18 DMAs), then epilogue hides them ----
        STAGE(c1, 0); STAGE(c1, 1); STAGE(c1, 2);
        STAGE(c1, 3); STAGE(c1, 4); STAGE(c1, 5);
        FENCE;                                 // pin stages BEFORE epi loads

        // ---- epilogue: pure-register. Lane owns pixels w(mi) and 4 whole
        //      channels (quad*4+c4); acc slot for (c4,p): idx=c4*9+p,
        //      ni=idx/4, j=idx%4 -- all compile-time. No LDS. ----
        #pragma unroll
        for (int mi = 0; mi < 2; ++mi) {
            const int w = (wv << 5) + (mi << 4) + lrow;      // this lane's pixel
            #pragma unroll
            for (int c4 = 0; c4 < 4; ++c4) {
                const int cg = (chunk << 4) + (quad << 2) + c4;  // channel
                const float* bp = bias + cg * 9;
                const float* xc = x + ((size_t)((b << 8) + cg) << 14);
                float sum = 0.f;
                #pragma unroll
                for (int p = 0; p < 9; ++p) {
                    const int idx = c4 * 9 + p;
                    const int ni = idx >> 2, j = idx & 3;
                    const float yv = acc[mi][ni][j];
                    const int hh = h + p / 3 - 1, ww = w + p % 3 - 1;
                    float xv = 0.f;
                    if ((unsigned)hh < 128u && (unsigned)ww < 128u)
                        xv = xc[(hh << 7) + ww];             // fp32 patch
                    sum += (yv + bp[p]) * xv;
                }
                out[((size_t)((b << 8) + cg) << 14) + (h << 7) + w] = sum;
            }
        }
    }
}

extern "C" void kernel_launch(void* const* d_in, const int* in_sizes, int n_in,
                              void* d_out, int out_size, void* d_ws, size_t ws_size,
                              hipStream_t stream) {
    const float* x    = (const float*)d_in[0];   // 4*256*128*128
    const float* W    = (const float*)d_in[1];   // 2304*256
    const float* bias = (const float*)d_in[2];   // 2304
    float* out = (float*)d_out;

    unsigned char* Wb = (unsigned char*)d_ws;    // 1,179,648 B

    wconv_kernel<<<288, 256, 0, stream>>>(W, Wb);
    dfgemm_kernel<<<512, 256, 0, stream>>>(Wb, x, bias, out);
}